// Round 7
// baseline (105.878 us; speedup 1.0000x reference)
//
#include <hip/hip_runtime.h>

#define Bv 2
#define Wv 1024
#define Dv 1024
#define Rv 16

typedef __bf16 bf16;
typedef __attribute__((ext_vector_type(8))) __bf16 bf16x8;
typedef __attribute__((ext_vector_type(4))) __bf16 bf16x4;
typedef __attribute__((ext_vector_type(4))) float f32x4;

static __device__ __forceinline__ float sigmoidf_(float x) {
    return 1.0f / (1.0f + expf(-x));
}

static __device__ __forceinline__ void gload_lds16(const void* g, void* l) {
    __builtin_amdgcn_global_load_lds(
        (const __attribute__((address_space(1))) unsigned int*)g,
        (__attribute__((address_space(3))) unsigned int*)l, 16, 0, 0);
}

// ---------------- unified prep ----------------
// blocks: [0,1024)        proj_wT  (f32 [1024][1024] -> bf16 [1024][1024])
//         [1024,3072)     up_wT    (f32 [1024][2048] -> bf16 [2048][1024]) x n2[row]
//         [3072,5120)     down_wT  (f32 [2048][1024] -> bf16 [1024][2048])
//         [5120,7168)     hT       (f32 h[b][1024][1024] -> bf16 [b][1024][1024], 2 batches)
//         [7168,7296)     uvT      ([32][1024] bf16, x n1[d])
//         [7296,9344)     inv1     (per-row rsqrt(mean(h^2)+eps), 2048 rows)
__global__ void prep_kernel(const float* __restrict__ h,
                            const float* __restrict__ proj_w, const float* __restrict__ up_w,
                            const float* __restrict__ down_w,
                            const float* __restrict__ u, const float* __restrict__ v,
                            const float* __restrict__ n1, const float* __restrict__ n2,
                            bf16* __restrict__ proj_wT, bf16* __restrict__ up_wT,
                            bf16* __restrict__ down_wT, bf16* __restrict__ hT,
                            bf16* __restrict__ uvT, float* __restrict__ inv1g) {
    __shared__ float tile[32][33];
    __shared__ float wsum[4];
    int blk = blockIdx.x;
    int t = threadIdx.x;
    if (blk >= 7296) {  // inv1: one block per row
        int row = blk - 7296;
        float4 x = *(const float4*)(h + (size_t)row * Dv + t * 4);
        float ss = x.x * x.x + x.y * x.y + x.z * x.z + x.w * x.w;
        for (int off = 32; off > 0; off >>= 1) ss += __shfl_down(ss, off);
        int lane = t & 63, wid = t >> 6;
        if (lane == 0) wsum[wid] = ss;
        __syncthreads();
        if (t == 0) {
            float tot = wsum[0] + wsum[1] + wsum[2] + wsum[3];
            inv1g[row] = rsqrtf(tot * (1.0f / Dv) + 1e-8f);
        }
        return;
    }
    if (blk >= 7168) {  // uvT x n1
        int i = (blk - 7168) * 256 + t;
        int rcol = i >> 10, d = i & (Wv - 1);
        float val = (rcol < Rv) ? u[(size_t)d * Rv + rcol] : v[(size_t)d * Rv + (rcol - Rv)];
        uvT[i] = (bf16)(val * n1[d]);
        return;
    }
    const float* src;
    const float* rscale = nullptr;  // per-source-row scale
    bf16* dst;
    int rows, cols, r0, c0;
    if (blk < 1024) {
        src = proj_w; dst = proj_wT; rows = 1024; cols = 1024;
        c0 = (blk & 31) * 32; r0 = (blk >> 5) * 32;
    } else if (blk < 3072) {
        int idx = blk - 1024;
        src = up_w; dst = up_wT; rows = 1024; cols = 2048; rscale = n2;
        c0 = (idx & 63) * 32; r0 = (idx >> 6) * 32;
    } else if (blk < 5120) {
        int idx = blk - 3072;
        src = down_w; dst = down_wT; rows = 2048; cols = 1024;
        c0 = (idx & 31) * 32; r0 = (idx >> 5) * 32;
    } else {
        int idx = blk - 5120;
        int b = idx >> 10; idx &= 1023;
        src = h + (size_t)b * Wv * Dv; dst = hT + (size_t)b * Dv * Wv;
        rows = 1024; cols = 1024;
        c0 = (idx & 31) * 32; r0 = (idx >> 5) * 32;
    }
    int r = t >> 3, c4 = (t & 7) * 4;
    float4 x = *(const float4*)(src + (size_t)(r0 + r) * cols + c0 + c4);
    float sc = rscale ? rscale[r0 + r] : 1.0f;
    tile[r][c4 + 0] = x.x * sc;
    tile[r][c4 + 1] = x.y * sc;
    tile[r][c4 + 2] = x.z * sc;
    tile[r][c4 + 3] = x.w * sc;
    __syncthreads();
    int n = t >> 3, k4 = (t & 7) * 4;
    bf16x4 ob = {(bf16)tile[k4 + 0][n], (bf16)tile[k4 + 1][n],
                 (bf16)tile[k4 + 2][n], (bf16)tile[k4 + 3][n]};
    *(bf16x4*)(dst + (size_t)(c0 + n) * rows + r0 + k4) = ob;
}

// ---------------- inv2: per-row rsqrt(mean(h2b^2)+eps), bf16 input ----------------
__global__ void inv2_kernel(const bf16* __restrict__ x, float* __restrict__ inv2g) {
    int row = blockIdx.x;
    int t = threadIdx.x;
    bf16x4 vb = *(const bf16x4*)(x + (size_t)row * Dv + t * 4);
    float a0 = (float)vb[0], a1 = (float)vb[1], a2 = (float)vb[2], a3 = (float)vb[3];
    float ss = a0 * a0 + a1 * a1 + a2 * a2 + a3 * a3;
    for (int off = 32; off > 0; off >>= 1) ss += __shfl_down(ss, off);
    __shared__ float wsum[4];
    int lane = t & 63, wid = t >> 6;
    if (lane == 0) wsum[wid] = ss;
    __syncthreads();
    if (t == 0) {
        float tot = wsum[0] + wsum[1] + wsum[2] + wsum[3];
        inv2g[row] = rsqrtf(tot * (1.0f / Dv) + 1e-8f);
    }
}

// ---------------- qk via MFMA from raw h (inv1 cancels in l2norm) ----------------
// Qs[i][r] = q*gamma_r^i ; Ks[j][r] = k*gamma_r^(-j) * inv1[j]
__global__ __launch_bounds__(256) void qk_mfma(
    const float* __restrict__ h,    // [B*W][D] f32
    const bf16* __restrict__ uvT,   // [32][D] (x n1)
    const float* __restrict__ decay_logit,
    const float* __restrict__ inv1g,
    bf16* __restrict__ Qs, bf16* __restrict__ Ks) {  // [B*W][16]
    int t = threadIdx.x, lane = t & 63, wid = t >> 6;
    int wm = wid >> 1, wn = wid & 1;
    int row0 = blockIdx.x * 32 + wm * 16;
    const float* Arow = h + (size_t)(row0 + (lane & 15)) * Dv + (lane >> 4) * 8;
    const bf16* Brow = uvT + (size_t)(wn * 16 + (lane & 15)) * Dv + (lane >> 4) * 8;
    f32x4 acc = {};
#pragma unroll 8
    for (int k0 = 0; k0 < Dv; k0 += 32) {
        float4 a0 = *(const float4*)(Arow + k0);
        float4 a1 = *(const float4*)(Arow + k0 + 4);
        bf16x8 a = {(bf16)a0.x, (bf16)a0.y, (bf16)a0.z, (bf16)a0.w,
                    (bf16)a1.x, (bf16)a1.y, (bf16)a1.z, (bf16)a1.w};
        bf16x8 b = *(const bf16x8*)(Brow + k0);
        acc = __builtin_amdgcn_mfma_f32_16x16x32_bf16(a, b, acc, 0, 0, 0);
    }
    int col = lane & 15;  // r index
    float dl = decay_logit[col];
    float gamma = 0.85f + 0.15f * sigmoidf_(dl);
    float logg = log2f(gamma);
#pragma unroll
    for (int r = 0; r < 4; ++r) {
        float vv = acc[r];
        float ss = vv * vv;
#pragma unroll
        for (int m = 1; m < 16; m <<= 1) ss += __shfl_xor(ss, m);
        float nrm = fmaxf(sqrtf(ss), 1e-8f);
        float val = vv / nrm;
        int grow = row0 + (lane >> 4) * 4 + r;
        int i = grow & (Wv - 1);
        if (wn == 0) {
            float pw = exp2f((float)i * logg);
            Qs[(size_t)grow * Rv + col] = (bf16)(val * pw);
        } else {
            float pwi = exp2f(-(float)i * logg) * inv1g[grow];
            Ks[(size_t)grow * Rv + col] = (bf16)(val * pwi);
        }
    }
}

// ---------------- S~ = gate*kb*inv1[j] + alpha*(Q~ @ Ks~^T), causal ----------------
__global__ __launch_bounds__(256) void sbuild_mfma(
    const bf16* __restrict__ Qs, const bf16* __restrict__ Ks,
    const float* __restrict__ kbase,
    const float* __restrict__ gate_logit,
    const float* __restrict__ alpha_logit,
    const float* __restrict__ inv1g,
    bf16* __restrict__ S) {
    int it = blockIdx.y, jt = blockIdx.x;
    if (jt > it) return;
    int b = blockIdx.z;
    int t = threadIdx.x, lane = t & 63, wid = t >> 6;
    int wm = wid >> 1, wn = wid & 1;
    int i0 = it * 64, j0 = jt * 64;
    int l15 = lane & 15, chunk = lane >> 4;
    bf16x8 af[2], bfr[2];
    bf16x8 z8 = {};
#pragma unroll
    for (int mi = 0; mi < 2; ++mi)
        af[mi] = (chunk < 2)
            ? *(const bf16x8*)(Qs + (size_t)(b * Wv + i0 + wm * 32 + mi * 16 + l15) * Rv + chunk * 8)
            : z8;
#pragma unroll
    for (int ni = 0; ni < 2; ++ni)
        bfr[ni] = (chunk < 2)
            ? *(const bf16x8*)(Ks + (size_t)(b * Wv + j0 + wn * 32 + ni * 16 + l15) * Rv + chunk * 8)
            : z8;
    f32x4 acc[2][2] = {};
#pragma unroll
    for (int mi = 0; mi < 2; ++mi)
#pragma unroll
        for (int ni = 0; ni < 2; ++ni)
            acc[mi][ni] = __builtin_amdgcn_mfma_f32_16x16x32_bf16(af[mi], bfr[ni], acc[mi][ni], 0, 0, 0);
    float gate = sigmoidf_(gate_logit[0]);
    float alpha = sigmoidf_(alpha_logit[0]);
#pragma unroll
    for (int mi = 0; mi < 2; ++mi)
#pragma unroll
        for (int ni = 0; ni < 2; ++ni) {
            int j = j0 + wn * 32 + ni * 16 + l15;
            float invj = inv1g[b * Wv + j];
#pragma unroll
            for (int r = 0; r < 4; ++r) {
                int i = i0 + wm * 32 + mi * 16 + chunk * 4 + r;
                float s = (j <= i) ? gate * kbase[(size_t)i * Wv + j] * invj + alpha * acc[mi][ni][r] : 0.f;
                S[((size_t)b * Wv + i) * Wv + j] = (bf16)s;
            }
        }
}

// ---------------- MFMA GEMM (round-5 structure): BM=BN=64, BK=128, 2 barriers/K-step ----
// C = [gelu]([rowscale]*[colscale]*(A @ Bt^T) + bias) [+ res]
// RES: 0 none, 1 f32, 2 bf16.
template <bool GELU, bool OUT_BF16, int RES, bool CAUSAL, bool RS, bool CS>
__global__ __launch_bounds__(256, 3) void mfma_gemm(
    const bf16* __restrict__ A, const bf16* __restrict__ Bt,
    const float* __restrict__ bias, const void* __restrict__ res,
    const float* __restrict__ rowscale, const float* __restrict__ colscale,
    void* __restrict__ Cout, int M, int N, int K,
    long sA, long sB, long sC) {
    constexpr int BM = 64, BN = 64, BK = 128;
    __shared__ bf16 As[BM * BK];
    __shared__ bf16 Bs[BN * BK];
    int bz = blockIdx.z;
    A += (size_t)bz * sA;
    Bt += (size_t)bz * sB;
    const int m0 = blockIdx.y * BM, n0 = blockIdx.x * BN;
    const int t = threadIdx.x;
    const int lane = t & 63, wid = t >> 6;
    const int wm = wid >> 1, wn = wid & 1;
    f32x4 acc[2][2] = {};

    const int Klim = CAUSAL ? (m0 + BM < K ? m0 + BM : K) : K;

    const int srow = t >> 4;
    const int fcs = (t & 15) ^ (srow & 7);

    const int q = lane >> 4, s = lane & 7, l15 = lane & 15;

    for (int k0 = 0; k0 < Klim; k0 += BK) {
        __syncthreads();
#pragma unroll
        for (int it = 0; it < 4; ++it) {
            int r = srow + it * 16;
            gload_lds16(A + (size_t)(m0 + r) * K + k0 + fcs * 8,
                        As + it * 2048 + wid * 512);
        }
#pragma unroll
        for (int it = 0; it < 4; ++it) {
            int r = srow + it * 16;
            gload_lds16(Bt + (size_t)(n0 + r) * K + k0 + fcs * 8,
                        Bs + it * 2048 + wid * 512);
        }
        __syncthreads();

        bf16x8 af[2][4], bfr[2][4];
#pragma unroll
        for (int mi = 0; mi < 2; ++mi)
#pragma unroll
            for (int kk = 0; kk < 4; ++kk) {
                af[mi][kk] = *(const bf16x8*)&As[(wm * 32 + mi * 16 + l15) * BK + (((kk * 4 + q) ^ s) * 8)];
                bfr[mi][kk] = *(const bf16x8*)&Bs[(wn * 32 + mi * 16 + l15) * BK + (((kk * 4 + q) ^ s) * 8)];
            }
#pragma unroll
        for (int kk = 0; kk < 4; ++kk)
#pragma unroll
            for (int mi = 0; mi < 2; ++mi)
#pragma unroll
                for (int ni = 0; ni < 2; ++ni)
                    acc[mi][ni] = __builtin_amdgcn_mfma_f32_16x16x32_bf16(
                        af[mi][kk], bfr[ni][kk], acc[mi][ni], 0, 0, 0);
    }

    const int row_base = m0 + wm * 32;
    const int col_base = n0 + wn * 32;
#pragma unroll
    for (int mi = 0; mi < 2; ++mi) {
#pragma unroll
        for (int ni = 0; ni < 2; ++ni) {
            int col = col_base + ni * 16 + l15;
            float bv = bias ? bias[col] : 0.f;
            float cs = CS ? colscale[col] : 1.0f;
#pragma unroll
            for (int r = 0; r < 4; ++r) {
                int row = row_base + mi * 16 + q * 4 + r;
                float val = acc[mi][ni][r];
                if (RS) val *= rowscale[row];
                if (CS) val *= cs;
                val += bv;
                if (GELU) val = 0.5f * val * (1.0f + erff(val * 0.7071067811865476f));
                if (RES == 1)
                    val += ((const float*)res)[(size_t)bz * sC + (size_t)row * N + col];
                else if (RES == 2)
                    val += (float)((const bf16*)res)[(size_t)bz * sC + (size_t)row * N + col];
                if (OUT_BF16)
                    ((bf16*)Cout)[(size_t)bz * sC + (size_t)row * N + col] = (bf16)val;
                else
                    ((float*)Cout)[(size_t)bz * sC + (size_t)row * N + col] = val;
            }
        }
    }
}

extern "C" void kernel_launch(void* const* d_in, const int* in_sizes, int n_in,
                              void* d_out, int out_size, void* d_ws, size_t ws_size,
                              hipStream_t stream) {
    const float* h = (const float*)d_in[0];
    const float* decay_logit = (const float*)d_in[1];
    const float* k_base = (const float*)d_in[2];
    const float* gate_logit = (const float*)d_in[3];
    const float* u = (const float*)d_in[4];
    const float* v = (const float*)d_in[5];
    const float* alpha_logit = (const float*)d_in[6];
    const float* proj_w = (const float*)d_in[7];
    const float* proj_b = (const float*)d_in[8];
    const float* n1 = (const float*)d_in[9];
    const float* n2 = (const float*)d_in[10];
    const float* up_w = (const float*)d_in[11];
    const float* up_b = (const float*)d_in[12];
    const float* down_w = (const float*)d_in[13];
    const float* down_b = (const float*)d_in[14];
    float* out = (float*)d_out;

    char* ws = (char*)d_ws;
    bf16* hT = (bf16*)ws;         ws += (size_t)Bv * Dv * Wv * 2;       // 4 MB
    bf16* uvT = (bf16*)ws;        ws += (size_t)32 * Wv * 2;            // 64 KB
    bf16* Qs = (bf16*)ws;         ws += (size_t)Bv * Wv * Rv * 2;       // 64 KB
    bf16* Ks = (bf16*)ws;         ws += (size_t)Bv * Wv * Rv * 2;       // 64 KB
    float* inv1g = (float*)ws;    ws += (size_t)Bv * Wv * 4;            // 8 KB
    float* inv2g = (float*)ws;    ws += (size_t)Bv * Wv * 4;            // 8 KB
    bf16* S = (bf16*)ws;          ws += (size_t)Bv * Wv * Wv * 2;       // 4 MB
    bf16* out_s = (bf16*)ws;      ws += (size_t)Bv * Wv * Dv * 2;       // 4 MB
    bf16* h2b = (bf16*)ws;        ws += (size_t)Bv * Wv * Dv * 2;       // 4 MB
    bf16* g = (bf16*)ws;          ws += (size_t)Bv * Wv * 2 * Dv * 2;   // 8 MB
    bf16* proj_wT = (bf16*)ws;    ws += (size_t)Dv * Dv * 2;            // 2 MB
    bf16* up_wT = (bf16*)ws;      ws += (size_t)2 * Dv * Dv * 2;        // 4 MB
    bf16* down_wT = (bf16*)ws;    ws += (size_t)2 * Dv * Dv * 2;        // 4 MB

    int rows = Bv * Wv;  // 2048

    // 1. prep: weight transposes (+n2 fold), hT, uvT (+n1 fold), inv1
    prep_kernel<<<9344, 256, 0, stream>>>(h, proj_w, up_w, down_w, u, v, n1, n2,
                                          proj_wT, up_wT, down_wT, hT, uvT, inv1g);
    // 2. q,k via MFMA (gamma + inv1 folding)
    qk_mfma<<<rows / 32, 256, 0, stream>>>(h, uvT, decay_logit, inv1g, Qs, Ks);
    // 3. S~ = gate*kb*inv1 + alpha*(Q~ @ Ks~^T), causal tiles
    sbuild_mfma<<<dim3(Wv / 64, Wv / 64, Bv), 256, 0, stream>>>(
        Qs, Ks, k_base, gate_logit, alpha_logit, inv1g, S);
    // 4. out_s = (S~ @ h) * n1[col]  (batched, causal-K, bf16 out)
    mfma_gemm<false, true, 0, true, false, true><<<dim3(Dv / 64, Wv / 64, Bv), 256, 0, stream>>>(
        S, hT, nullptr, nullptr, nullptr, n1, out_s, Wv, Dv, Wv,
        (long)Wv * Wv, (long)Dv * Wv, (long)Wv * Dv);
    // 5. h2b = h + out_s @ proj_w + proj_b  (bf16 out, f32 res)
    mfma_gemm<false, true, 1, false, false, false><<<dim3(Dv / 64, rows / 64, 1), 256, 0, stream>>>(
        out_s, proj_wT, proj_b, h, nullptr, nullptr, h2b, rows, Dv, Dv, 0, 0, 0);
    // 6. inv2 per row of h2b
    inv2_kernel<<<rows, 256, 0, stream>>>(h2b, inv2g);
    // 7. g = gelu(inv2[r]*(h2b @ up_wT(n2-folded)) + up_b)  (bf16 out)
    mfma_gemm<true, true, 0, false, true, false><<<dim3(2 * Dv / 64, rows / 64, 1), 256, 0, stream>>>(
        h2b, up_wT, up_b, nullptr, inv2g, nullptr, g, rows, 2 * Dv, Dv, 0, 0, 0);
    // 8. out = h2b + g @ down_w + down_b  (f32 out, bf16 res)
    mfma_gemm<false, false, 2, false, false, false><<<dim3(Dv / 64, rows / 64, 1), 256, 0, stream>>>(
        g, down_wT, down_b, h2b, nullptr, nullptr, out, rows, Dv, 2 * Dv, 0, 0, 0);
}

// Round 8
// 97.440 us; speedup vs baseline: 1.0866x; 1.0866x over previous
//
#include <hip/hip_runtime.h>

#define Bv 2
#define Wv 1024
#define Dv 1024
#define Rv 16

typedef __bf16 bf16;
typedef __attribute__((ext_vector_type(8))) __bf16 bf16x8;
typedef __attribute__((ext_vector_type(4))) __bf16 bf16x4;
typedef __attribute__((ext_vector_type(4))) float f32x4;

static __device__ __forceinline__ float sigmoidf_(float x) {
    return 1.0f / (1.0f + expf(-x));
}

static __device__ __forceinline__ void gload_lds16(const void* g, void* l) {
    __builtin_amdgcn_global_load_lds(
        (const __attribute__((address_space(1))) unsigned int*)g,
        (__attribute__((address_space(3))) unsigned int*)l, 16, 0, 0);
}

// ---------------- RMSNorm: one block per row, 256 threads, D=1024, bf16 out ----------------
__global__ void rmsnorm_kernel(const float* __restrict__ x,
                               const float* __restrict__ scale,
                               bf16* __restrict__ outb) {
    int row = blockIdx.x;
    int t = threadIdx.x;
    float4 v = *(const float4*)(x + (size_t)row * Dv + t * 4);
    float ss = v.x * v.x + v.y * v.y + v.z * v.z + v.w * v.w;
    for (int off = 32; off > 0; off >>= 1) ss += __shfl_down(ss, off);
    __shared__ float wsum[4];
    __shared__ float inv_s;
    int lane = t & 63, wid = t >> 6;
    if (lane == 0) wsum[wid] = ss;
    __syncthreads();
    if (t == 0) {
        float tot = wsum[0] + wsum[1] + wsum[2] + wsum[3];
        inv_s = rsqrtf(tot * (1.0f / Dv) + 1e-8f);
    }
    __syncthreads();
    float inv = inv_s;
    float4 sc = *(const float4*)(scale + t * 4);
    bf16x4 ob = {(bf16)(v.x * inv * sc.x), (bf16)(v.y * inv * sc.y),
                 (bf16)(v.z * inv * sc.z), (bf16)(v.w * inv * sc.w)};
    *(bf16x4*)(outb + (size_t)row * Dv + t * 4) = ob;
}

// ---------------- inv2: per-row rsqrt(mean(h2b^2)+eps), bf16 input ----------------
__global__ void inv2_kernel(const bf16* __restrict__ x, float* __restrict__ inv2g) {
    int row = blockIdx.x;
    int t = threadIdx.x;
    bf16x4 vb = *(const bf16x4*)(x + (size_t)row * Dv + t * 4);
    float a0 = (float)vb[0], a1 = (float)vb[1], a2 = (float)vb[2], a3 = (float)vb[3];
    float ss = a0 * a0 + a1 * a1 + a2 * a2 + a3 * a3;
    for (int off = 32; off > 0; off >>= 1) ss += __shfl_down(ss, off);
    __shared__ float wsum[4];
    int lane = t & 63, wid = t >> 6;
    if (lane == 0) wsum[wid] = ss;
    __syncthreads();
    if (t == 0) {
        float tot = wsum[0] + wsum[1] + wsum[2] + wsum[3];
        inv2g[row] = rsqrtf(tot * (1.0f / Dv) + 1e-8f);
    }
}

// ---------------- unified prep: weight transposes (+n2 fold on up_w) + h_normT + uvT ----------------
// blocks: [0,1024) proj_wT | [1024,3072) up_wT(xn2) | [3072,5120) down_wT
//         [5120,7168) h_normT (2 batches) | [7168,7296) uvT
__global__ void prep_kernel(const float* __restrict__ proj_w, const float* __restrict__ up_w,
                            const float* __restrict__ down_w,
                            const float* __restrict__ u, const float* __restrict__ v,
                            const float* __restrict__ n2,
                            const bf16* __restrict__ hnb,
                            bf16* __restrict__ proj_wT, bf16* __restrict__ up_wT,
                            bf16* __restrict__ down_wT, bf16* __restrict__ h_normT,
                            bf16* __restrict__ uvT) {
    __shared__ float tile[32][33];
    int blk = blockIdx.x;
    int t = threadIdx.x;
    if (blk >= 7168) {  // uvT
        int i = (blk - 7168) * 256 + t;
        int rcol = i >> 10, d = i & (Wv - 1);
        float val = (rcol < Rv) ? u[(size_t)d * Rv + rcol] : v[(size_t)d * Rv + (rcol - Rv)];
        uvT[i] = (bf16)val;
        return;
    }
    const void* src;
    const float* rscale = nullptr;
    bf16* dst;
    int rows, cols, r0, c0;
    bool f32src = true;
    if (blk < 1024) {
        src = proj_w; dst = proj_wT; rows = 1024; cols = 1024;
        c0 = (blk & 31) * 32; r0 = (blk >> 5) * 32;
    } else if (blk < 3072) {
        int idx = blk - 1024;
        src = up_w; dst = up_wT; rows = 1024; cols = 2048; rscale = n2;
        c0 = (idx & 63) * 32; r0 = (idx >> 6) * 32;
    } else if (blk < 5120) {
        int idx = blk - 3072;
        src = down_w; dst = down_wT; rows = 2048; cols = 1024;
        c0 = (idx & 31) * 32; r0 = (idx >> 5) * 32;
    } else {
        int idx = blk - 5120;
        int b = idx >> 10; idx &= 1023;
        src = hnb + (size_t)b * Wv * Dv; dst = h_normT + (size_t)b * Dv * Wv;
        rows = 1024; cols = 1024; f32src = false;
        c0 = (idx & 31) * 32; r0 = (idx >> 5) * 32;
    }
    int r = t >> 3, c4 = (t & 7) * 4;
    float vv[4];
    if (f32src) {
        float4 x = *(const float4*)((const float*)src + (size_t)(r0 + r) * cols + c0 + c4);
        vv[0] = x.x; vv[1] = x.y; vv[2] = x.z; vv[3] = x.w;
    } else {
        bf16x4 x = *(const bf16x4*)((const bf16*)src + (size_t)(r0 + r) * cols + c0 + c4);
        vv[0] = (float)x[0]; vv[1] = (float)x[1]; vv[2] = (float)x[2]; vv[3] = (float)x[3];
    }
    float sc = rscale ? rscale[r0 + r] : 1.0f;
    tile[r][c4 + 0] = vv[0] * sc;
    tile[r][c4 + 1] = vv[1] * sc;
    tile[r][c4 + 2] = vv[2] * sc;
    tile[r][c4 + 3] = vv[3] * sc;
    __syncthreads();
    int n = t >> 3, k4 = (t & 7) * 4;
    bf16x4 ob = {(bf16)tile[k4 + 0][n], (bf16)tile[k4 + 1][n],
                 (bf16)tile[k4 + 2][n], (bf16)tile[k4 + 3][n]};
    *(bf16x4*)(dst + (size_t)(c0 + n) * rows + r0 + k4) = ob;
}

// ---------------- qk via MFMA: [Q|K] = l2norm(hnb @ uvT^T) with gamma folding ----------------
__global__ __launch_bounds__(256) void qk_mfma(
    const bf16* __restrict__ hnb,   // [B*W][D]
    const bf16* __restrict__ uvT,   // [32][D]
    const float* __restrict__ decay_logit,
    bf16* __restrict__ Qs, bf16* __restrict__ Ks) {  // [B*W][16]
    int t = threadIdx.x, lane = t & 63, wid = t >> 6;
    int wm = wid >> 1, wn = wid & 1;
    int row0 = blockIdx.x * 32 + wm * 16;
    const bf16* Arow = hnb + (size_t)(row0 + (lane & 15)) * Dv + (lane >> 4) * 8;
    const bf16* Brow = uvT + (size_t)(wn * 16 + (lane & 15)) * Dv + (lane >> 4) * 8;
    f32x4 acc = {};
#pragma unroll 8
    for (int k0 = 0; k0 < Dv; k0 += 32) {
        bf16x8 a = *(const bf16x8*)(Arow + k0);
        bf16x8 b = *(const bf16x8*)(Brow + k0);
        acc = __builtin_amdgcn_mfma_f32_16x16x32_bf16(a, b, acc, 0, 0, 0);
    }
    int col = lane & 15;  // r index
    float dl = decay_logit[col];
    float gamma = 0.85f + 0.15f * sigmoidf_(dl);
    float logg = log2f(gamma);
#pragma unroll
    for (int r = 0; r < 4; ++r) {
        float vv = acc[r];
        float ss = vv * vv;
#pragma unroll
        for (int m = 1; m < 16; m <<= 1) ss += __shfl_xor(ss, m);
        float nrm = fmaxf(sqrtf(ss), 1e-8f);
        float val = vv / nrm;
        int grow = row0 + (lane >> 4) * 4 + r;
        int i = grow & (Wv - 1);
        if (wn == 0) {
            float pw = exp2f((float)i * logg);
            Qs[(size_t)grow * Rv + col] = (bf16)(val * pw);
        } else {
            float pwi = exp2f(-(float)i * logg);
            Ks[(size_t)grow * Rv + col] = (bf16)(val * pwi);
        }
    }
}

// ---------------- S tile build via MFMA: S = gate*kb + alpha*(Q~ @ K~^T), causal ----------------
__global__ __launch_bounds__(256) void sbuild_mfma(
    const bf16* __restrict__ Qs, const bf16* __restrict__ Ks,
    const float* __restrict__ kbase,
    const float* __restrict__ gate_logit,
    const float* __restrict__ alpha_logit,
    bf16* __restrict__ S) {
    int it = blockIdx.y, jt = blockIdx.x;
    if (jt > it) return;
    int b = blockIdx.z;
    int t = threadIdx.x, lane = t & 63, wid = t >> 6;
    int wm = wid >> 1, wn = wid & 1;
    int i0 = it * 64, j0 = jt * 64;
    int l15 = lane & 15, chunk = lane >> 4;
    bf16x8 af[2], bfr[2];
    bf16x8 z8 = {};
#pragma unroll
    for (int mi = 0; mi < 2; ++mi)
        af[mi] = (chunk < 2)
            ? *(const bf16x8*)(Qs + (size_t)(b * Wv + i0 + wm * 32 + mi * 16 + l15) * Rv + chunk * 8)
            : z8;
#pragma unroll
    for (int ni = 0; ni < 2; ++ni)
        bfr[ni] = (chunk < 2)
            ? *(const bf16x8*)(Ks + (size_t)(b * Wv + j0 + wn * 32 + ni * 16 + l15) * Rv + chunk * 8)
            : z8;
    f32x4 acc[2][2] = {};
#pragma unroll
    for (int mi = 0; mi < 2; ++mi)
#pragma unroll
        for (int ni = 0; ni < 2; ++ni)
            acc[mi][ni] = __builtin_amdgcn_mfma_f32_16x16x32_bf16(af[mi], bfr[ni], acc[mi][ni], 0, 0, 0);
    float gate = sigmoidf_(gate_logit[0]);
    float alpha = sigmoidf_(alpha_logit[0]);
#pragma unroll
    for (int mi = 0; mi < 2; ++mi)
#pragma unroll
        for (int ni = 0; ni < 2; ++ni) {
            int j = j0 + wn * 32 + ni * 16 + l15;
#pragma unroll
            for (int r = 0; r < 4; ++r) {
                int i = i0 + wm * 32 + mi * 16 + chunk * 4 + r;
                float s = (j <= i) ? gate * kbase[(size_t)i * Wv + j] + alpha * acc[mi][ni][r] : 0.f;
                S[((size_t)b * Wv + i) * Wv + j] = (bf16)s;
            }
        }
}

// ---------------- MFMA GEMM (r5 structure + XCD swizzle): BM=BN=64, BK=128 ----------------
// C = [gelu]([rowscale]*(A @ Bt^T) + bias) [+ res]; RES: 0 none, 1 f32, 2 bf16.
// Grid must have total blocks divisible by 8 (all our grids are).
template <bool GELU, bool OUT_BF16, int RES, bool CAUSAL, bool RS>
__global__ __launch_bounds__(256, 3) void mfma_gemm(
    const bf16* __restrict__ A, const bf16* __restrict__ Bt,
    const float* __restrict__ bias, const void* __restrict__ res,
    const float* __restrict__ rowscale,
    void* __restrict__ Cout, int M, int N, int K,
    long sA, long sB, long sC) {
    constexpr int BM = 64, BN = 64, BK = 128;
    __shared__ bf16 As[BM * BK];
    __shared__ bf16 Bs[BN * BK];

    // XCD-aware bijective swizzle: give each XCD a contiguous chunk of logical tiles.
    const int gx = gridDim.x, gy = gridDim.y;
    int flat = blockIdx.x + gx * (blockIdx.y + gy * blockIdx.z);
    const int nwg = gx * gy * gridDim.z;
    const int cpx = nwg >> 3;
    int swz = (flat & 7) * cpx + (flat >> 3);
    const int bx = swz % gx;
    int tmp = swz / gx;
    const int by = tmp % gy;
    const int bz = tmp / gy;

    A += (size_t)bz * sA;
    Bt += (size_t)bz * sB;
    const int m0 = by * BM, n0 = bx * BN;
    const int t = threadIdx.x;
    const int lane = t & 63, wid = t >> 6;
    const int wm = wid >> 1, wn = wid & 1;
    f32x4 acc[2][2] = {};

    const int Klim = CAUSAL ? (m0 + BM < K ? m0 + BM : K) : K;

    const int srow = t >> 4;
    const int fcs = (t & 15) ^ (srow & 7);

    const int q = lane >> 4, s = lane & 7, l15 = lane & 15;

    for (int k0 = 0; k0 < Klim; k0 += BK) {
        __syncthreads();
#pragma unroll
        for (int it = 0; it < 4; ++it) {
            int r = srow + it * 16;
            gload_lds16(A + (size_t)(m0 + r) * K + k0 + fcs * 8,
                        As + it * 2048 + wid * 512);
        }
#pragma unroll
        for (int it = 0; it < 4; ++it) {
            int r = srow + it * 16;
            gload_lds16(Bt + (size_t)(n0 + r) * K + k0 + fcs * 8,
                        Bs + it * 2048 + wid * 512);
        }
        __syncthreads();

        bf16x8 af[2][4], bfr[2][4];
#pragma unroll
        for (int mi = 0; mi < 2; ++mi)
#pragma unroll
            for (int kk = 0; kk < 4; ++kk) {
                af[mi][kk] = *(const bf16x8*)&As[(wm * 32 + mi * 16 + l15) * BK + (((kk * 4 + q) ^ s) * 8)];
                bfr[mi][kk] = *(const bf16x8*)&Bs[(wn * 32 + mi * 16 + l15) * BK + (((kk * 4 + q) ^ s) * 8)];
            }
#pragma unroll
        for (int kk = 0; kk < 4; ++kk)
#pragma unroll
            for (int mi = 0; mi < 2; ++mi)
#pragma unroll
                for (int ni = 0; ni < 2; ++ni)
                    acc[mi][ni] = __builtin_amdgcn_mfma_f32_16x16x32_bf16(
                        af[mi][kk], bfr[ni][kk], acc[mi][ni], 0, 0, 0);
    }

    const int row_base = m0 + wm * 32;
    const int col_base = n0 + wn * 32;
#pragma unroll
    for (int mi = 0; mi < 2; ++mi) {
#pragma unroll
        for (int ni = 0; ni < 2; ++ni) {
            int col = col_base + ni * 16 + l15;
            float bv = bias ? bias[col] : 0.f;
#pragma unroll
            for (int r = 0; r < 4; ++r) {
                int row = row_base + mi * 16 + q * 4 + r;
                float val = acc[mi][ni][r];
                if (RS) val *= rowscale[row];
                val += bv;
                if (GELU) val = 0.5f * val * (1.0f + erff(val * 0.7071067811865476f));
                if (RES == 1)
                    val += ((const float*)res)[(size_t)bz * sC + (size_t)row * N + col];
                else if (RES == 2)
                    val += (float)((const bf16*)res)[(size_t)bz * sC + (size_t)row * N + col];
                if (OUT_BF16)
                    ((bf16*)Cout)[(size_t)bz * sC + (size_t)row * N + col] = (bf16)val;
                else
                    ((float*)Cout)[(size_t)bz * sC + (size_t)row * N + col] = val;
            }
        }
    }
}

extern "C" void kernel_launch(void* const* d_in, const int* in_sizes, int n_in,
                              void* d_out, int out_size, void* d_ws, size_t ws_size,
                              hipStream_t stream) {
    const float* h = (const float*)d_in[0];
    const float* decay_logit = (const float*)d_in[1];
    const float* k_base = (const float*)d_in[2];
    const float* gate_logit = (const float*)d_in[3];
    const float* u = (const float*)d_in[4];
    const float* v = (const float*)d_in[5];
    const float* alpha_logit = (const float*)d_in[6];
    const float* proj_w = (const float*)d_in[7];
    const float* proj_b = (const float*)d_in[8];
    const float* n1 = (const float*)d_in[9];
    const float* n2 = (const float*)d_in[10];
    const float* up_w = (const float*)d_in[11];
    const float* up_b = (const float*)d_in[12];
    const float* down_w = (const float*)d_in[13];
    const float* down_b = (const float*)d_in[14];
    float* out = (float*)d_out;

    char* ws = (char*)d_ws;
    bf16* hnb = (bf16*)ws;        ws += (size_t)Bv * Wv * Dv * 2;       // 4 MB
    bf16* h_normT = (bf16*)ws;    ws += (size_t)Bv * Dv * Wv * 2;       // 4 MB
    bf16* uvT = (bf16*)ws;        ws += (size_t)32 * Wv * 2;            // 64 KB
    bf16* Qs = (bf16*)ws;         ws += (size_t)Bv * Wv * Rv * 2;       // 64 KB
    bf16* Ks = (bf16*)ws;         ws += (size_t)Bv * Wv * Rv * 2;       // 64 KB
    float* inv2g = (float*)ws;    ws += (size_t)Bv * Wv * 4;            // 8 KB
    bf16* S = (bf16*)ws;          ws += (size_t)Bv * Wv * Wv * 2;       // 4 MB
    bf16* out_s = (bf16*)ws;      ws += (size_t)Bv * Wv * Dv * 2;       // 4 MB
    bf16* h2b = (bf16*)ws;        ws += (size_t)Bv * Wv * Dv * 2;       // 4 MB
    bf16* g = (bf16*)ws;          ws += (size_t)Bv * Wv * 2 * Dv * 2;   // 8 MB
    bf16* proj_wT = (bf16*)ws;    ws += (size_t)Dv * Dv * 2;            // 2 MB
    bf16* up_wT = (bf16*)ws;      ws += (size_t)2 * Dv * Dv * 2;        // 4 MB
    bf16* down_wT = (bf16*)ws;    ws += (size_t)2 * Dv * Dv * 2;        // 4 MB

    int rows = Bv * Wv;  // 2048

    // 1. hnb = rmsnorm(h, norm1_scale) bf16
    rmsnorm_kernel<<<rows, 256, 0, stream>>>(h, n1, hnb);
    // 2. all transposes (+n2 fold on up_w) + uvT in one launch
    prep_kernel<<<7296, 256, 0, stream>>>(proj_w, up_w, down_w, u, v, n2, hnb,
                                          proj_wT, up_wT, down_wT, h_normT, uvT);
    // 3. q,k via MFMA with gamma folding
    qk_mfma<<<rows / 32, 256, 0, stream>>>(hnb, uvT, decay_logit, Qs, Ks);
    // 4. S = gate*kb + alpha*(Q~ @ K~^T), causal tiles
    sbuild_mfma<<<dim3(Wv / 64, Wv / 64, Bv), 256, 0, stream>>>(
        Qs, Ks, k_base, gate_logit, alpha_logit, S);
    // 5. out_s = S @ h_norm  (batched, causal-K, bf16 out)
    mfma_gemm<false, true, 0, true, false><<<dim3(Dv / 64, Wv / 64, Bv), 256, 0, stream>>>(
        S, h_normT, nullptr, nullptr, nullptr, out_s, Wv, Dv, Wv,
        (long)Wv * Wv, (long)Dv * Wv, (long)Wv * Dv);
    // 6. h2b = h + out_s @ proj_w + proj_b  (bf16 out, f32 res)
    mfma_gemm<false, true, 1, false, false><<<dim3(Dv / 64, rows / 64, 1), 256, 0, stream>>>(
        out_s, proj_wT, proj_b, h, nullptr, h2b, rows, Dv, Dv, 0, 0, 0);
    // 7. inv2 per row of h2b
    inv2_kernel<<<rows, 256, 0, stream>>>(h2b, inv2g);
    // 8. g = gelu(inv2[r]*(h2b @ up_wT(n2-folded)) + up_b)  (bf16 out)
    mfma_gemm<true, true, 0, false, true><<<dim3(2 * Dv / 64, rows / 64, 1), 256, 0, stream>>>(
        h2b, up_wT, up_b, nullptr, inv2g, g, rows, 2 * Dv, Dv, 0, 0, 0);
    // 9. out = h2b + g @ down_w + down_b  (f32 out, bf16 res)
    mfma_gemm<false, false, 2, false, false><<<dim3(Dv / 64, rows / 64, 1), 256, 0, stream>>>(
        g, down_wT, down_b, h2b, nullptr, out, rows, Dv, 2 * Dv, 0, 0, 0);
}